// Round 1
// baseline (489.896 us; speedup 1.0000x reference)
//
#include <hip/hip_runtime.h>
#include <math.h>

// DiffGatedTopK: x (16384 x 4096 fp32). Per row: k=614 top-k mask, gain =
// sigmoid(top1-top2)*3+1, out = x*mask*gain.
//
// One block per row. Row staged in LDS as order-preserving uint32; 4-pass
// 8-bit radix select finds the EXACT k-th-largest bit pattern so that
// duplicate values straddling the k boundary are tie-broken by lowest index
// (matching jax.lax.top_k) via a rare ordered-ballot path.

#define D      4096
#define K      614            // int(4096 * 0.15)
#define BLOCK  256
#define NWAVES 4

__device__ __forceinline__ unsigned int f2ord(float f) {
    unsigned int b = __float_as_uint(f);
    return (b & 0x80000000u) ? ~b : (b | 0x80000000u);
}
__device__ __forceinline__ float ord2f(unsigned int u) {
    unsigned int b = (u & 0x80000000u) ? (u ^ 0x80000000u) : ~u;
    return __uint_as_float(b);
}

__global__ __launch_bounds__(BLOCK, 1)
void diffgated_topk(const float* __restrict__ x, float* __restrict__ out) {
    const int row  = blockIdx.x;
    const int tid  = threadIdx.x;
    const int wave = tid >> 6;
    const int lane = tid & 63;
    const float* xrow = x + (size_t)row * D;
    float*       orow = out + (size_t)row * D;

    __shared__ unsigned int u_lds[D];          // 16 KiB: ordered-uint row
    __shared__ int hist[NWAVES][256];          // 4 KiB: per-wave privatized
    __shared__ int scan_s[256];                // 1 KiB: suffix sums
    __shared__ unsigned int sh_prefix;
    __shared__ int sh_krem, sh_numeq, sh_eqbase;
    __shared__ float sh_w1[NWAVES], sh_w2[NWAVES], sh_gain;
    __shared__ int sh_wsum[NWAVES];

    // ---- init ----
    #pragma unroll
    for (int w = 0; w < NWAVES; ++w) hist[w][tid] = 0;
    if (tid == 0) { sh_prefix = 0u; sh_krem = K; sh_eqbase = 0; }
    __syncthreads();

    // ---- stage row -> LDS (ordered uints), histogram top byte, track top-2 ----
    float m1 = -INFINITY, m2 = -INFINITY;
    for (int i = tid; i < D / 4; i += BLOCK) {
        float4 v = ((const float4*)xrow)[i];
        float vs[4] = { v.x, v.y, v.z, v.w };
        uint4 uu;
        unsigned int* up = (unsigned int*)&uu;
        #pragma unroll
        for (int j = 0; j < 4; ++j) {
            float f = vs[j];
            if (f > m1) { m2 = m1; m1 = f; } else if (f > m2) { m2 = f; }
            unsigned int u = f2ord(f);
            up[j] = u;
            atomicAdd(&hist[wave][u >> 24], 1);
        }
        ((uint4*)u_lds)[i] = uu;
    }

    // ---- top-2 reduction (pairwise combine) ----
    #pragma unroll
    for (int off = 32; off > 0; off >>= 1) {
        float o1 = __shfl_down(m1, off);
        float o2 = __shfl_down(m2, off);
        float hi = fmaxf(m1, o1);
        float lo = fminf(m1, o1);
        m2 = fmaxf(lo, fmaxf(m2, o2));
        m1 = hi;
    }
    if (lane == 0) { sh_w1[wave] = m1; sh_w2[wave] = m2; }
    __syncthreads();
    if (tid == 0) {
        float a1 = sh_w1[0], a2 = sh_w2[0];
        #pragma unroll
        for (int w = 1; w < NWAVES; ++w) {
            float b1 = sh_w1[w], b2 = sh_w2[w];
            float hi = fmaxf(a1, b1), lo = fminf(a1, b1);
            a2 = fmaxf(lo, fmaxf(a2, b2));
            a1 = hi;
        }
        float diff = a1 - a2;                    // >= 0
        float sig  = 1.0f / (1.0f + expf(-diff));
        sh_gain = sig * 3.0f + 1.0f;
    }

    // ---- 4-pass radix select (MSB -> LSB), exact k-th-largest pattern ----
    for (int pass = 0; pass < 4; ++pass) {
        const int shift = 24 - 8 * pass;
        int csum = hist[0][tid] + hist[1][tid] + hist[2][tid] + hist[3][tid];
        scan_s[tid] = csum;
        __syncthreads();
        // suffix (reverse inclusive) Hillis-Steele scan over 256 bins
        for (int off = 1; off < 256; off <<= 1) {
            int v = (tid + off < 256) ? scan_s[tid + off] : 0;
            __syncthreads();
            scan_s[tid] += v;
            __syncthreads();
        }
        int S = scan_s[tid];                 // count of elems with bin >= tid
        int krem = sh_krem;
        __syncthreads();
        if (S >= krem && S - csum < krem) {  // bin tid holds the k-th largest
            sh_prefix |= ((unsigned int)tid) << shift;
            sh_krem = krem - (S - csum);
            sh_numeq = csum;
        }
        __syncthreads();
        if (pass < 3) {
            #pragma unroll
            for (int w = 0; w < NWAVES; ++w) hist[w][tid] = 0;
            __syncthreads();
            const unsigned int pfx = sh_prefix;
            const int shift2 = shift - 8;
            for (int i = tid; i < D / 4; i += BLOCK) {
                uint4 uu = ((const uint4*)u_lds)[i];
                const unsigned int* up = (const unsigned int*)&uu;
                #pragma unroll
                for (int j = 0; j < 4; ++j) {
                    unsigned int u = up[j];
                    if (((u ^ pfx) >> shift) == 0)
                        atomicAdd(&hist[wave][(u >> shift2) & 0xFF], 1);
                }
            }
            __syncthreads();
        }
    }

    const float gain        = sh_gain;
    const unsigned int ut   = sh_prefix;   // exact k-th-largest bit pattern
    const int needed        = sh_krem;     // # of ==ut elements to include
    const int numeq         = sh_numeq;    // # of ==ut elements in the row

    // ---- output ----
    if (numeq == needed) {
        // common case: all elements equal to the threshold are included
        for (int i = tid; i < D / 4; i += BLOCK) {
            uint4 uu = ((const uint4*)u_lds)[i];
            const unsigned int* up = (const unsigned int*)&uu;
            float4 o;
            float* op = (float*)&o;
            #pragma unroll
            for (int j = 0; j < 4; ++j) {
                unsigned int u = up[j];
                op[j] = (u >= ut) ? ord2f(u) * gain : 0.0f;
            }
            ((float4*)orow)[i] = o;
        }
    } else {
        // rare: duplicates straddle the k boundary -> lowest-index-first
        for (int c0 = 0; c0 < D; c0 += BLOCK) {
            unsigned int u = u_lds[c0 + tid];
            bool eq = (u == ut);
            unsigned long long bal = __ballot(eq);
            if (lane == 0) sh_wsum[wave] = __popcll(bal);
            __syncthreads();
            int before = sh_eqbase;
            for (int w = 0; w < wave; ++w) before += sh_wsum[w];
            int myrank = before + __popcll(bal & ((1ull << lane) - 1ull));
            float f = 0.0f;
            if (u > ut || (eq && myrank < needed)) f = ord2f(u) * gain;
            orow[c0 + tid] = f;
            __syncthreads();
            if (tid == 0) {
                int s = 0;
                #pragma unroll
                for (int w = 0; w < NWAVES; ++w) s += sh_wsum[w];
                sh_eqbase += s;
            }
            __syncthreads();
        }
    }
}

extern "C" void kernel_launch(void* const* d_in, const int* in_sizes, int n_in,
                              void* d_out, int out_size, void* d_ws, size_t ws_size,
                              hipStream_t stream) {
    const float* x = (const float*)d_in[0];
    float* out = (float*)d_out;
    const int rows = in_sizes[0] / D;   // 16384
    diffgated_topk<<<dim3(rows), dim3(BLOCK), 0, stream>>>(x, out);
}